// Round 9
// baseline (228.663 us; speedup 1.0000x reference)
//
#include <hip/hip_runtime.h>
#include <stdint.h>
#include <stddef.h>

// Problem constants
#define BB 8
#define CC 16
#define DD 192
#define OCC 4
#define OHH 50
#define OWW 200

#define LDP 200   // padded LDS row stride in bf16 elements (192 + 8)
#define CH  24    // 8-element chunks per 192 row

typedef __attribute__((ext_vector_type(8))) short s8v;   // 8 bf16 = 16B (MFMA A/B frag)
typedef __attribute__((ext_vector_type(4))) short s4v;   // 4 bf16 = 8B
typedef __attribute__((ext_vector_type(4))) float f4v;   // 4 fp32
typedef __attribute__((ext_vector_type(4))) float f32x4; // MFMA C/D frag

__device__ __forceinline__ short rne_bf16(float f) {
  uint32_t u = __float_as_uint(f);
  u += 0x7fffu + ((u >> 16) & 1u);
  return (short)(u >> 16);
}
__device__ __forceinline__ float bf2f(short s) {
  return __uint_as_float(((uint32_t)(uint16_t)s) << 16);
}

// ---------------- fused prep kernel (transposes only; R-cvt folded into stageA) ----
// z-segmented grid: [0, NTX)      transpose_x   (x fp32 -> XTb bf16 transposed)
//                   [NTX, +NPT)   transpose_pt  (PT fp32 -> PTTb bf16 transposed)
#define NTX (BB * CC * 36)    // 4608 blocks: 6x6 32-tiles per outer
#define NPT (OCC * CC * 42)   // 2688 blocks: 6x7 32-tiles per outer

__global__ __launch_bounds__(256) void prep(const float* __restrict__ x,
                                            const float* __restrict__ PT,
                                            short* __restrict__ XTb,
                                            short* __restrict__ PTTb) {
  __shared__ float tile[32][33];
  const int z = blockIdx.x;
  const int tid = threadIdx.x;
  const int tx = tid & 31, ty = tid >> 5;
  if (z < NTX) {
    int outer = z / 36, rem = z % 36;
    int p0 = (rem / 6) * 32, q0 = (rem % 6) * 32;
    const float* src = x + (size_t)outer * DD * DD;
    for (int r = ty; r < 32; r += 8)
      tile[r][tx] = src[(size_t)(p0 + r) * DD + q0 + tx];
    __syncthreads();
    short* dst = XTb + (size_t)outer * DD * DD;
    for (int r = ty; r < 32; r += 8)
      dst[(size_t)(q0 + r) * DD + p0 + tx] = rne_bf16(tile[tx][r]);
  } else {
    int z2 = z - NTX;
    int outer = z2 / 42, rem = z2 % 42;
    int q0 = (rem / 7) * 32, n0 = (rem % 7) * 32;
    const float* src = PT + (size_t)outer * DD * OWW;
    for (int r = ty; r < 32; r += 8)
      tile[r][tx] = (n0 + tx < OWW) ? src[(size_t)(q0 + r) * OWW + n0 + tx] : 0.f;
    __syncthreads();
    short* dst = PTTb + (size_t)outer * OWW * DD;
    for (int r = ty; r < 32; r += 8)
      if (n0 + r < OWW) dst[(size_t)(n0 + r) * DD + q0 + tx] = rne_bf16(tile[tx][r]);
  }
}

// ---------------- stage A ----------------
// y[b,i] = sum_j R[i,j] @ x[b,j] @ R[i,j]^T, split over jg halves.
// mm1: T^T[q][m] = sum_p XT[q][p] R[m][p]   (A = XT rows in lds2, B = R rows in ldsR)
// mm2: y[m][n]   = sum_q T[m][q] R[n][q]    (A = T rows in lds2, B = R rows in ldsR)
// 512 threads = 8 waves (R0-proven 75.3 us config; 256-VGPR headroom).
// Changes vs R0: (a) R staged from fp32 directly (cvt kernel eliminated; same
// rne_bf16 -> bit-identical); (b) no XCD swizzle (R0 27.7MB vs R5 78MB FETCH at
// equal time); (c) R-fragments for kc<3 cached in registers across mm1->mm2
// (both mms read the SAME ldsR addresses: B-rows (wm*3+c)*16+lane15, same kc).
// VGPR: acc_y 72 + acc_t 72 + rf 36 + temps ~30 => ~210 < 256 (2 waves/SIMD).
__global__ __launch_bounds__(512) void stageA(const float* __restrict__ Rf,
                                              const short* __restrict__ XTb,
                                              short* __restrict__ ypart) {
  __shared__ __align__(16) short ldsR[DD * LDP];
  __shared__ __align__(16) short lds2[DD * LDP];
  const int tid = threadIdx.x;
  const int bx = blockIdx.x;
  const int b = bx >> 5, i = (bx >> 1) & 15, jg = bx & 1;
  const int lane15 = tid & 15, quad = (tid & 63) >> 4;
  const int wid = tid >> 6;
  const int wm = wid & 3;   // 0..3 -> 3 tiles each (B-operand dim)
  const int wq = wid >> 2;  // 0..1 -> 6 tiles each (A-operand dim)

  f32x4 acc_y[6][3];
  #pragma unroll
  for (int a = 0; a < 6; ++a)
    #pragma unroll
    for (int c = 0; c < 3; ++c) acc_y[a][c] = (f32x4){0.f, 0.f, 0.f, 0.f};

  for (int jj = 0; jj < 8; ++jj) {
    const int j = jg * 8 + jj;
    const float* srcR = Rf + (size_t)(i * CC + j) * (DD * DD);
    const short* srcX = XTb + (size_t)(b * CC + j) * (DD * DD);
    __syncthreads();  // previous iter done reading ldsR/lds2
    for (int c = tid; c < DD * CH; c += 512) {
      int row = c / CH, col = c % CH;
      const float* s = srcR + (size_t)c * 8;
      f4v v0 = *(const f4v*)(s);
      f4v v1 = *(const f4v*)(s + 4);
      s8v o;
      #pragma unroll
      for (int r = 0; r < 4; ++r) o[r] = rne_bf16(v0[r]);
      #pragma unroll
      for (int r = 0; r < 4; ++r) o[r + 4] = rne_bf16(v1[r]);
      *(s8v*)(&ldsR[row * LDP + col * 8]) = o;
      *(s8v*)(&lds2[row * LDP + col * 8]) = *(const s8v*)(srcX + (size_t)c * 8);
    }
    __syncthreads();

    // mm1: T^T  (A = XT rows -> wq covers 6 q-tiles; B = R rows -> wm covers 3 m-tiles)
    f32x4 acc_t[6][3];
    #pragma unroll
    for (int a = 0; a < 6; ++a)
      #pragma unroll
      for (int c = 0; c < 3; ++c) acc_t[a][c] = (f32x4){0.f, 0.f, 0.f, 0.f};

    s8v rf[3][3];  // R-fragments for kc=0..2, reused by mm2 (same addresses)
    #pragma unroll
    for (int kc = 0; kc < 6; ++kc) {
      s8v af[6], bf[3];
      #pragma unroll
      for (int a = 0; a < 6; ++a)
        af[a] = *(const s8v*)(&lds2[((wq * 6 + a) * 16 + lane15) * LDP + kc * 32 + quad * 8]);
      #pragma unroll
      for (int c = 0; c < 3; ++c) {
        bf[c] = *(const s8v*)(&ldsR[((wm * 3 + c) * 16 + lane15) * LDP + kc * 32 + quad * 8]);
        if (kc < 3) rf[kc][c] = bf[c];
      }
      #pragma unroll
      for (int a = 0; a < 6; ++a)
        #pragma unroll
        for (int c = 0; c < 3; ++c)
          acc_t[a][c] = __builtin_amdgcn_mfma_f32_16x16x32_bf16(af[a], bf[c], acc_t[a][c], 0, 0, 0);
    }
    __syncthreads();

    // pack T[m][q] (bf16) into lds2
    #pragma unroll
    for (int a = 0; a < 6; ++a) {
      #pragma unroll
      for (int c = 0; c < 3; ++c) {
        s4v pk;
        #pragma unroll
        for (int r = 0; r < 4; ++r) pk[r] = rne_bf16(acc_t[a][c][r]);
        int m = (wm * 3 + c) * 16 + lane15;
        int q0 = (wq * 6 + a) * 16 + quad * 4;
        *(s4v*)(&lds2[m * LDP + q0]) = pk;
      }
    }
    __syncthreads();

    // mm2: y[m][n] += T rows x R rows  (A = T -> wq covers 6 m-tiles; B = R -> wm covers 3 n-tiles)
    #pragma unroll
    for (int kc = 0; kc < 6; ++kc) {
      s8v af[6], bf[3];
      #pragma unroll
      for (int a = 0; a < 6; ++a)
        af[a] = *(const s8v*)(&lds2[((wq * 6 + a) * 16 + lane15) * LDP + kc * 32 + quad * 8]);
      #pragma unroll
      for (int c = 0; c < 3; ++c)
        bf[c] = (kc < 3) ? rf[kc][c]
                         : *(const s8v*)(&ldsR[((wm * 3 + c) * 16 + lane15) * LDP + kc * 32 + quad * 8]);
      #pragma unroll
      for (int a = 0; a < 6; ++a)
        #pragma unroll
        for (int c = 0; c < 3; ++c)
          acc_y[a][c] = __builtin_amdgcn_mfma_f32_16x16x32_bf16(af[a], bf[c], acc_y[a][c], 0, 0, 0);
    }
  }

  // pack y^T [n][m] into lds2, then coalesced store
  __syncthreads();
  #pragma unroll
  for (int a = 0; a < 6; ++a) {
    #pragma unroll
    for (int c = 0; c < 3; ++c) {
      s4v pk;
      #pragma unroll
      for (int r = 0; r < 4; ++r) pk[r] = rne_bf16(acc_y[a][c][r]);
      int n = (wm * 3 + c) * 16 + lane15;       // B-row = n (col of y)
      int m0 = (wq * 6 + a) * 16 + quad * 4;    // A-row = m, 4 consecutive
      *(s4v*)(&lds2[n * LDP + m0]) = pk;
    }
  }
  __syncthreads();
  {
    short* dst = ypart + (size_t)(jg * (BB * CC) + b * CC + i) * (DD * DD);
    for (int c = tid; c < DD * CH; c += 512) {
      int row = c / CH, col = c % CH;
      *(s8v*)(dst + (size_t)c * 8) = *(const s8v*)(&lds2[row * LDP + col * 8]);
    }
  }
}

// ---------------- fused stage B ----------------
// out[b,oc] = sum_j P[oc,j] @ y[b,j] @ PT[oc,j]
// y = ypart0 + ypart1 summed during staging; P staged from fp32 (cvt fused).
// Final store: atomicAdd into out (harness memsets out to 0 before launch);
// each out element receives exactly 4 adds (one per jg partial).
#define PROWS 64
#define PTROWS 128
__global__ __launch_bounds__(512, 2) void fusedB(const short* __restrict__ ypart,
                                                 const float* __restrict__ Pf,
                                                 const short* __restrict__ PTTb,
                                                 float* __restrict__ out) {
  __shared__ __align__(16) short ldsYT[DD * LDP];     // 76.8 KB; rows 0..63 reused for U
  __shared__ __align__(16) short ldsP[PROWS * LDP];   // 25.6 KB
  __shared__ __align__(16) short ldsPT[PTROWS * LDP]; // 51.2 KB
  const int tid = threadIdx.x;
  const int bx0 = blockIdx.x;
  const int bx = (bx0 & 7) * 32 + (bx0 >> 3);   // XCD-chunked swizzle
  const int jg = bx & 3, nh = (bx >> 2) & 1, oc = (bx >> 3) & 3, b = bx >> 5;
  const int lane15 = tid & 15, quad = (tid & 63) >> 4;
  const int wid = tid >> 6;
  // mm_b1 wave grid: 4 (q) x 2 (m)
  const int wq1 = wid >> 1, wm1 = wid & 1;
  // mm_b2 wave grid: 2 (m) x 4 (n)
  const int wm2 = wid & 1, wn2 = wid >> 1;

  f32x4 acc_o[2][2];
  #pragma unroll
  for (int a = 0; a < 2; ++a)
    #pragma unroll
    for (int e = 0; e < 2; ++e) acc_o[a][e] = (f32x4){0.f, 0.f, 0.f, 0.f};

  const s8v z = {0, 0, 0, 0, 0, 0, 0, 0};
  for (int jj = 0; jj < 4; ++jj) {
    const int j = jg * 4 + jj;
    __syncthreads();  // prev iter done reading U/ldsP/ldsPT
    {
      const short* sy0 = ypart + (size_t)(b * CC + j) * (DD * DD);
      const short* sy1 = sy0 + (size_t)(BB * CC) * (DD * DD);
      for (int c = tid; c < DD * CH; c += 512) {
        int row = c / CH, col = c % CH;
        s8v v0 = *(const s8v*)(sy0 + (size_t)c * 8);
        s8v v1 = *(const s8v*)(sy1 + (size_t)c * 8);
        s8v o;
        #pragma unroll
        for (int r = 0; r < 8; ++r) o[r] = rne_bf16(bf2f(v0[r]) + bf2f(v1[r]));
        *(s8v*)(&ldsYT[row * LDP + col * 8]) = o;
      }
      const float* sp = Pf + (size_t)(oc * CC + j) * (OHH * DD);
      for (int c = tid; c < PROWS * CH; c += 512) {
        int row = c / CH, col = c % CH;
        s8v w = z;
        if (c < OHH * CH) {
          f4v v0 = *(const f4v*)(sp + (size_t)c * 8);
          f4v v1 = *(const f4v*)(sp + (size_t)c * 8 + 4);
          #pragma unroll
          for (int r = 0; r < 4; ++r) w[r] = rne_bf16(v0[r]);
          #pragma unroll
          for (int r = 0; r < 4; ++r) w[r + 4] = rne_bf16(v1[r]);
        }
        *(s8v*)(&ldsP[row * LDP + col * 8]) = w;
      }
      const short* st = PTTb + (size_t)(oc * CC + j) * (OWW * DD) + (size_t)nh * 100 * DD;
      for (int c = tid; c < PTROWS * CH; c += 512) {
        int row = c / CH, col = c % CH;
        *(s8v*)(&ldsPT[row * LDP + col * 8]) =
            (c < 100 * CH) ? *(const s8v*)(st + (size_t)c * 8) : z;
      }
    }
    __syncthreads();

    // mm_b1: U^T[q][m]; wq1 -> 3 q-tiles, wm1 -> 2 m-tiles
    f32x4 acc_t[3][2];
    #pragma unroll
    for (int a = 0; a < 3; ++a)
      #pragma unroll
      for (int c = 0; c < 2; ++c) acc_t[a][c] = (f32x4){0.f, 0.f, 0.f, 0.f};
    #pragma unroll
    for (int kc = 0; kc < 6; ++kc) {
      s8v af[3], bf[2];
      #pragma unroll
      for (int a = 0; a < 3; ++a)
        af[a] = *(const s8v*)(&ldsYT[((wq1 * 3 + a) * 16 + lane15) * LDP + kc * 32 + quad * 8]);
      #pragma unroll
      for (int c = 0; c < 2; ++c)
        bf[c] = *(const s8v*)(&ldsP[((wm1 * 2 + c) * 16 + lane15) * LDP + kc * 32 + quad * 8]);
      #pragma unroll
      for (int a = 0; a < 3; ++a)
        #pragma unroll
        for (int c = 0; c < 2; ++c)
          acc_t[a][c] = __builtin_amdgcn_mfma_f32_16x16x32_bf16(af[a], bf[c], acc_t[a][c], 0, 0, 0);
    }
    __syncthreads();  // yT fully consumed

    // pack U[m][q] into ldsYT rows 0..63
    #pragma unroll
    for (int a = 0; a < 3; ++a) {
      #pragma unroll
      for (int c = 0; c < 2; ++c) {
        s4v pk;
        #pragma unroll
        for (int r = 0; r < 4; ++r) pk[r] = rne_bf16(acc_t[a][c][r]);
        int m = (wm1 * 2 + c) * 16 + lane15;
        int q0 = (wq1 * 3 + a) * 16 + quad * 4;
        *(s4v*)(&ldsYT[m * LDP + q0]) = pk;
      }
    }
    __syncthreads();

    // mm_b2: out[m][n] += U rows x PT^T rows; wm2 -> 2 m-tiles, wn2 -> 2 n-tiles
    #pragma unroll
    for (int kc = 0; kc < 6; ++kc) {
      s8v af[2], bf[2];
      #pragma unroll
      for (int a = 0; a < 2; ++a)
        af[a] = *(const s8v*)(&ldsYT[((wm2 * 2 + a) * 16 + lane15) * LDP + kc * 32 + quad * 8]);
      #pragma unroll
      for (int e = 0; e < 2; ++e)
        bf[e] = *(const s8v*)(&ldsPT[((wn2 * 2 + e) * 16 + lane15) * LDP + kc * 32 + quad * 8]);
      #pragma unroll
      for (int a = 0; a < 2; ++a)
        #pragma unroll
        for (int e = 0; e < 2; ++e)
          acc_o[a][e] = __builtin_amdgcn_mfma_f32_16x16x32_bf16(af[a], bf[e], acc_o[a][e], 0, 0, 0);
    }
  }

  // atomic accumulate partial into out[b*OCC+oc][m][nh*100 + n]
  float* dst = out + (size_t)(b * OCC + oc) * (OHH * OWW);
  #pragma unroll
  for (int a = 0; a < 2; ++a) {
    #pragma unroll
    for (int e = 0; e < 2; ++e) {
      int n = (wn2 * 2 + e) * 16 + lane15;
      if (n < 100) {
        #pragma unroll
        for (int r = 0; r < 4; ++r) {
          int m = (wm2 * 2 + a) * 16 + quad * 4 + r;
          if (m < OHH)
            atomicAdd(&dst[(size_t)m * OWW + nh * 100 + n], acc_o[a][e][r]);
        }
      }
    }
  }
}

// ---------------- launcher ----------------

extern "C" void kernel_launch(void* const* d_in, const int* in_sizes, int n_in,
                              void* d_out, int out_size, void* d_ws, size_t ws_size,
                              hipStream_t stream) {
  const float* x  = (const float*)d_in[0];
  const float* R  = (const float*)d_in[1];
  const float* P  = (const float*)d_in[2];
  const float* PT = (const float*)d_in[3];
  float* out = (float*)d_out;

  short* W = (short*)d_ws;
  const size_t nX   = (size_t)BB * CC * DD * DD;     // 4,718,592
  const size_t nPT  = (size_t)OCC * CC * OWW * DD;   // 2,457,600
  short* XTb   = W;
  short* PTTb  = XTb + nX;
  short* ypart = PTTb + nPT;                         // 2 halves

  prep<<<NTX + NPT, 256, 0, stream>>>(x, PT, XTb, PTTb);

  stageA<<<BB * CC * 2, 512, 0, stream>>>(R, XTb, ypart);
  fusedB<<<BB * OCC * 2 * 4, 512, 0, stream>>>(ypart, P, PTTb, out);
}

// Round 10
// 214.313 us; speedup vs baseline: 1.0670x; 1.0670x over previous
//
#include <hip/hip_runtime.h>
#include <stdint.h>
#include <stddef.h>

// Problem constants
#define BB 8
#define CC 16
#define DD 192
#define OCC 4
#define OHH 50
#define OWW 200

#define LDP 200   // padded LDS row stride in bf16 elements (192 + 8)
#define CH  24    // 8-element chunks per 192 row

typedef __attribute__((ext_vector_type(8))) short s8v;   // 8 bf16 = 16B (MFMA A/B frag)
typedef __attribute__((ext_vector_type(4))) short s4v;   // 4 bf16 = 8B
typedef __attribute__((ext_vector_type(4))) float f4v;   // 4 fp32
typedef __attribute__((ext_vector_type(4))) float f32x4; // MFMA C/D frag

__device__ __forceinline__ short rne_bf16(float f) {
  uint32_t u = __float_as_uint(f);
  u += 0x7fffu + ((u >> 16) & 1u);
  return (short)(u >> 16);
}
__device__ __forceinline__ float bf2f(short s) {
  return __uint_as_float(((uint32_t)(uint16_t)s) << 16);
}

// ---------------- fused prep kernel ----------------
// z-segmented grid: [0, NTX)      transpose_x   (x fp32 -> XTb bf16 transposed)
//                   [NTX, +NPT)   transpose_pt  (PT fp32 -> PTTb bf16 transposed)
//                   [.., +NCV)    cvt R fp32 -> bf16  (kept SEPARATE from stageA:
//                   R9 proved folding cvt into stageA's serialized staging phase
//                   costs +22us; here it runs at full-GPU parallelism)
#define NTX (BB * CC * 36)    // 4608 blocks: 6x6 32-tiles per outer
#define NPT (OCC * CC * 42)   // 2688 blocks: 6x7 32-tiles per outer
#define NCV 9216              // (16*16*192*192/4)/256

__global__ __launch_bounds__(256) void prep(const float* __restrict__ x,
                                            const float* __restrict__ R,
                                            const float* __restrict__ PT,
                                            short* __restrict__ XTb,
                                            short* __restrict__ PTTb,
                                            short* __restrict__ Rb) {
  __shared__ float tile[32][33];
  const int z = blockIdx.x;
  const int tid = threadIdx.x;
  const int tx = tid & 31, ty = tid >> 5;
  if (z < NTX) {
    int outer = z / 36, rem = z % 36;
    int p0 = (rem / 6) * 32, q0 = (rem % 6) * 32;
    const float* src = x + (size_t)outer * DD * DD;
    for (int r = ty; r < 32; r += 8)
      tile[r][tx] = src[(size_t)(p0 + r) * DD + q0 + tx];
    __syncthreads();
    short* dst = XTb + (size_t)outer * DD * DD;
    for (int r = ty; r < 32; r += 8)
      dst[(size_t)(q0 + r) * DD + p0 + tx] = rne_bf16(tile[tx][r]);
  } else if (z < NTX + NPT) {
    int z2 = z - NTX;
    int outer = z2 / 42, rem = z2 % 42;
    int q0 = (rem / 7) * 32, n0 = (rem % 7) * 32;
    const float* src = PT + (size_t)outer * DD * OWW;
    for (int r = ty; r < 32; r += 8)
      tile[r][tx] = (n0 + tx < OWW) ? src[(size_t)(q0 + r) * OWW + n0 + tx] : 0.f;
    __syncthreads();
    short* dst = PTTb + (size_t)outer * OWW * DD;
    for (int r = ty; r < 32; r += 8)
      if (n0 + r < OWW) dst[(size_t)(n0 + r) * DD + q0 + tx] = rne_bf16(tile[tx][r]);
  } else {
    int idx = (z - NTX - NPT) * 256 + tid;   // exact: NCV*256 == nR/4
    f4v v = *(const f4v*)(R + (size_t)idx * 4);
    s4v o;
    #pragma unroll
    for (int r = 0; r < 4; ++r) o[r] = rne_bf16(v[r]);
    *(s4v*)(Rb + (size_t)idx * 4) = o;
  }
}

// ---------------- stage A ----------------
// EXACT R5 kernel (proven 74.8-75.2 us): 1024 threads = 16 waves, 4x4 wave grid,
// 3x3 16-tiles per wave, cached vector-load staging, LDP=200 padding,
// XCD-chunked blockIdx swizzle. Session ledger of slower variants -- do NOT
// reintroduce: direct-global A-frags (+70us, latency-exposed at 1 block/CU),
// register prefetch (VGPR spill -> scratch traffic, 2 attempts), global_load_lds
// (+50us, bypasses cache dedup of shared R/X slabs -> 292MB HBM), fp32-R staging
// in-kernel (+22us, VALU cvt inside serialized staging phase), rf-cache across
// mm1->mm2 (bundled regression R9). Structure runs at 773 TF ~= 86% of the
// 2-barrier-structure ceiling (~900 TF).
__global__ __launch_bounds__(1024) void stageA(const short* __restrict__ Rb,
                                               const short* __restrict__ XTb,
                                               short* __restrict__ ypart) {
  __shared__ __align__(16) short ldsR[DD * LDP];
  __shared__ __align__(16) short lds2[DD * LDP];
  const int tid = threadIdx.x;
  const int bx0 = blockIdx.x;
  const int bx = (bx0 & 7) * 32 + (bx0 >> 3);   // XCD-chunked swizzle (256 = 8*32, bijective)
  const int b = bx >> 5, i = (bx >> 1) & 15, jg = bx & 1;
  const int lane15 = tid & 15, quad = (tid & 63) >> 4;
  const int wid = tid >> 6;   // 0..15
  const int wm = wid & 3;     // 4 groups x 3 tiles (B-operand dim)
  const int wq = wid >> 2;    // 4 groups x 3 tiles (A-operand dim)

  f32x4 acc_y[3][3];
  #pragma unroll
  for (int a = 0; a < 3; ++a)
    #pragma unroll
    for (int c = 0; c < 3; ++c) acc_y[a][c] = (f32x4){0.f, 0.f, 0.f, 0.f};

  for (int jj = 0; jj < 8; ++jj) {
    const int j = jg * 8 + jj;
    const short* srcR = Rb + (size_t)(i * CC + j) * (DD * DD);
    const short* srcX = XTb + (size_t)(b * CC + j) * (DD * DD);
    __syncthreads();  // previous iter done reading ldsR/lds2
    for (int c = tid; c < DD * CH; c += 1024) {
      int row = c / CH, col = c % CH;
      *(s8v*)(&ldsR[row * LDP + col * 8]) = *(const s8v*)(srcR + (size_t)c * 8);
      *(s8v*)(&lds2[row * LDP + col * 8]) = *(const s8v*)(srcX + (size_t)c * 8);
    }
    __syncthreads();

    // mm1: T^T  (A = XT rows -> wq covers 3 q-tiles; B = R rows -> wm covers 3 m-tiles)
    f32x4 acc_t[3][3];
    #pragma unroll
    for (int a = 0; a < 3; ++a)
      #pragma unroll
      for (int c = 0; c < 3; ++c) acc_t[a][c] = (f32x4){0.f, 0.f, 0.f, 0.f};

    #pragma unroll
    for (int kc = 0; kc < 6; ++kc) {
      s8v af[3], bf[3];
      #pragma unroll
      for (int a = 0; a < 3; ++a)
        af[a] = *(const s8v*)(&lds2[((wq * 3 + a) * 16 + lane15) * LDP + kc * 32 + quad * 8]);
      #pragma unroll
      for (int c = 0; c < 3; ++c)
        bf[c] = *(const s8v*)(&ldsR[((wm * 3 + c) * 16 + lane15) * LDP + kc * 32 + quad * 8]);
      #pragma unroll
      for (int a = 0; a < 3; ++a)
        #pragma unroll
        for (int c = 0; c < 3; ++c)
          acc_t[a][c] = __builtin_amdgcn_mfma_f32_16x16x32_bf16(af[a], bf[c], acc_t[a][c], 0, 0, 0);
    }
    __syncthreads();   // X fully consumed

    // pack T[m][q] (bf16) into lds2
    #pragma unroll
    for (int a = 0; a < 3; ++a) {
      #pragma unroll
      for (int c = 0; c < 3; ++c) {
        s4v pk;
        #pragma unroll
        for (int r = 0; r < 4; ++r) pk[r] = rne_bf16(acc_t[a][c][r]);
        int m = (wm * 3 + c) * 16 + lane15;
        int q0 = (wq * 3 + a) * 16 + quad * 4;
        *(s4v*)(&lds2[m * LDP + q0]) = pk;
      }
    }
    __syncthreads();

    // mm2: y[m][n] += T rows x R rows  (A = T -> wq covers 3 m-tiles; B = R -> wm covers 3 n-tiles)
    #pragma unroll
    for (int kc = 0; kc < 6; ++kc) {
      s8v af[3], bf[3];
      #pragma unroll
      for (int a = 0; a < 3; ++a)
        af[a] = *(const s8v*)(&lds2[((wq * 3 + a) * 16 + lane15) * LDP + kc * 32 + quad * 8]);
      #pragma unroll
      for (int c = 0; c < 3; ++c)
        bf[c] = *(const s8v*)(&ldsR[((wm * 3 + c) * 16 + lane15) * LDP + kc * 32 + quad * 8]);
      #pragma unroll
      for (int a = 0; a < 3; ++a)
        #pragma unroll
        for (int c = 0; c < 3; ++c)
          acc_y[a][c] = __builtin_amdgcn_mfma_f32_16x16x32_bf16(af[a], bf[c], acc_y[a][c], 0, 0, 0);
    }
  }

  // pack y^T [n][m] into lds2, then coalesced store
  __syncthreads();
  #pragma unroll
  for (int a = 0; a < 3; ++a) {
    #pragma unroll
    for (int c = 0; c < 3; ++c) {
      s4v pk;
      #pragma unroll
      for (int r = 0; r < 4; ++r) pk[r] = rne_bf16(acc_y[a][c][r]);
      int n = (wm * 3 + c) * 16 + lane15;       // B-row = n (col of y)
      int m0 = (wq * 3 + a) * 16 + quad * 4;    // A-row = m, 4 consecutive
      *(s4v*)(&lds2[n * LDP + m0]) = pk;
    }
  }
  __syncthreads();
  {
    short* dst = ypart + (size_t)(jg * (BB * CC) + b * CC + i) * (DD * DD);
    for (int c = tid; c < DD * CH; c += 1024) {
      int row = c / CH, col = c % CH;
      *(s8v*)(dst + (size_t)c * 8) = *(const s8v*)(&lds2[row * LDP + col * 8]);
    }
  }
}

// ---------------- fused stage B ----------------
// out[b,oc] = sum_j P[oc,j] @ y[b,j] @ PT[oc,j]
// y = ypart0 + ypart1 summed during staging; P staged from fp32 (cvt fused).
// Final store: atomicAdd into out (harness memsets out to 0 before launch);
// each out element receives exactly 4 adds (one per jg partial) -> reduce_out
// kernel and partials buffer eliminated.
#define PROWS 64
#define PTROWS 128
__global__ __launch_bounds__(512, 2) void fusedB(const short* __restrict__ ypart,
                                                 const float* __restrict__ Pf,
                                                 const short* __restrict__ PTTb,
                                                 float* __restrict__ out) {
  __shared__ __align__(16) short ldsYT[DD * LDP];     // 76.8 KB; rows 0..63 reused for U
  __shared__ __align__(16) short ldsP[PROWS * LDP];   // 25.6 KB
  __shared__ __align__(16) short ldsPT[PTROWS * LDP]; // 51.2 KB
  const int tid = threadIdx.x;
  const int bx0 = blockIdx.x;
  const int bx = (bx0 & 7) * 32 + (bx0 >> 3);   // XCD-chunked swizzle
  const int jg = bx & 3, nh = (bx >> 2) & 1, oc = (bx >> 3) & 3, b = bx >> 5;
  const int lane15 = tid & 15, quad = (tid & 63) >> 4;
  const int wid = tid >> 6;
  // mm_b1 wave grid: 4 (q) x 2 (m)
  const int wq1 = wid >> 1, wm1 = wid & 1;
  // mm_b2 wave grid: 2 (m) x 4 (n)
  const int wm2 = wid & 1, wn2 = wid >> 1;

  f32x4 acc_o[2][2];
  #pragma unroll
  for (int a = 0; a < 2; ++a)
    #pragma unroll
    for (int e = 0; e < 2; ++e) acc_o[a][e] = (f32x4){0.f, 0.f, 0.f, 0.f};

  const s8v z = {0, 0, 0, 0, 0, 0, 0, 0};
  for (int jj = 0; jj < 4; ++jj) {
    const int j = jg * 4 + jj;
    __syncthreads();  // prev iter done reading U/ldsP/ldsPT
    {
      const short* sy0 = ypart + (size_t)(b * CC + j) * (DD * DD);
      const short* sy1 = sy0 + (size_t)(BB * CC) * (DD * DD);
      for (int c = tid; c < DD * CH; c += 512) {
        int row = c / CH, col = c % CH;
        s8v v0 = *(const s8v*)(sy0 + (size_t)c * 8);
        s8v v1 = *(const s8v*)(sy1 + (size_t)c * 8);
        s8v o;
        #pragma unroll
        for (int r = 0; r < 8; ++r) o[r] = rne_bf16(bf2f(v0[r]) + bf2f(v1[r]));
        *(s8v*)(&ldsYT[row * LDP + col * 8]) = o;
      }
      const float* sp = Pf + (size_t)(oc * CC + j) * (OHH * DD);
      for (int c = tid; c < PROWS * CH; c += 512) {
        int row = c / CH, col = c % CH;
        s8v w = z;
        if (c < OHH * CH) {
          f4v v0 = *(const f4v*)(sp + (size_t)c * 8);
          f4v v1 = *(const f4v*)(sp + (size_t)c * 8 + 4);
          #pragma unroll
          for (int r = 0; r < 4; ++r) w[r] = rne_bf16(v0[r]);
          #pragma unroll
          for (int r = 0; r < 4; ++r) w[r + 4] = rne_bf16(v1[r]);
        }
        *(s8v*)(&ldsP[row * LDP + col * 8]) = w;
      }
      const short* st = PTTb + (size_t)(oc * CC + j) * (OWW * DD) + (size_t)nh * 100 * DD;
      for (int c = tid; c < PTROWS * CH; c += 512) {
        int row = c / CH, col = c % CH;
        *(s8v*)(&ldsPT[row * LDP + col * 8]) =
            (c < 100 * CH) ? *(const s8v*)(st + (size_t)c * 8) : z;
      }
    }
    __syncthreads();

    // mm_b1: U^T[q][m]; wq1 -> 3 q-tiles, wm1 -> 2 m-tiles
    f32x4 acc_t[3][2];
    #pragma unroll
    for (int a = 0; a < 3; ++a)
      #pragma unroll
      for (int c = 0; c < 2; ++c) acc_t[a][c] = (f32x4){0.f, 0.f, 0.f, 0.f};
    #pragma unroll
    for (int kc = 0; kc < 6; ++kc) {
      s8v af[3], bf[2];
      #pragma unroll
      for (int a = 0; a < 3; ++a)
        af[a] = *(const s8v*)(&ldsYT[((wq1 * 3 + a) * 16 + lane15) * LDP + kc * 32 + quad * 8]);
      #pragma unroll
      for (int c = 0; c < 2; ++c)
        bf[c] = *(const s8v*)(&ldsP[((wm1 * 2 + c) * 16 + lane15) * LDP + kc * 32 + quad * 8]);
      #pragma unroll
      for (int a = 0; a < 3; ++a)
        #pragma unroll
        for (int c = 0; c < 2; ++c)
          acc_t[a][c] = __builtin_amdgcn_mfma_f32_16x16x32_bf16(af[a], bf[c], acc_t[a][c], 0, 0, 0);
    }
    __syncthreads();  // yT fully consumed

    // pack U[m][q] into ldsYT rows 0..63
    #pragma unroll
    for (int a = 0; a < 3; ++a) {
      #pragma unroll
      for (int c = 0; c < 2; ++c) {
        s4v pk;
        #pragma unroll
        for (int r = 0; r < 4; ++r) pk[r] = rne_bf16(acc_t[a][c][r]);
        int m = (wm1 * 2 + c) * 16 + lane15;
        int q0 = (wq1 * 3 + a) * 16 + quad * 4;
        *(s4v*)(&ldsYT[m * LDP + q0]) = pk;
      }
    }
    __syncthreads();

    // mm_b2: out[m][n] += U rows x PT^T rows; wm2 -> 2 m-tiles, wn2 -> 2 n-tiles
    #pragma unroll
    for (int kc = 0; kc < 6; ++kc) {
      s8v af[2], bf[2];
      #pragma unroll
      for (int a = 0; a < 2; ++a)
        af[a] = *(const s8v*)(&ldsYT[((wm2 * 2 + a) * 16 + lane15) * LDP + kc * 32 + quad * 8]);
      #pragma unroll
      for (int e = 0; e < 2; ++e)
        bf[e] = *(const s8v*)(&ldsPT[((wn2 * 2 + e) * 16 + lane15) * LDP + kc * 32 + quad * 8]);
      #pragma unroll
      for (int a = 0; a < 2; ++a)
        #pragma unroll
        for (int e = 0; e < 2; ++e)
          acc_o[a][e] = __builtin_amdgcn_mfma_f32_16x16x32_bf16(af[a], bf[e], acc_o[a][e], 0, 0, 0);
    }
  }

  // atomic accumulate partial into out[b*OCC+oc][m][nh*100 + n]
  float* dst = out + (size_t)(b * OCC + oc) * (OHH * OWW);
  #pragma unroll
  for (int a = 0; a < 2; ++a) {
    #pragma unroll
    for (int e = 0; e < 2; ++e) {
      int n = (wn2 * 2 + e) * 16 + lane15;
      if (n < 100) {
        #pragma unroll
        for (int r = 0; r < 4; ++r) {
          int m = (wm2 * 2 + a) * 16 + quad * 4 + r;
          if (m < OHH)
            atomicAdd(&dst[(size_t)m * OWW + nh * 100 + n], acc_o[a][e][r]);
        }
      }
    }
  }
}

// ---------------- launcher ----------------

extern "C" void kernel_launch(void* const* d_in, const int* in_sizes, int n_in,
                              void* d_out, int out_size, void* d_ws, size_t ws_size,
                              hipStream_t stream) {
  const float* x  = (const float*)d_in[0];
  const float* R  = (const float*)d_in[1];
  const float* P  = (const float*)d_in[2];
  const float* PT = (const float*)d_in[3];
  float* out = (float*)d_out;

  short* W = (short*)d_ws;
  const size_t nR   = (size_t)CC * CC * DD * DD;     // 9,437,184
  const size_t nX   = (size_t)BB * CC * DD * DD;     // 4,718,592
  const size_t nPT  = (size_t)OCC * CC * OWW * DD;   // 2,457,600
  short* Rb    = W;
  short* XTb   = Rb + nR;
  short* PTTb  = XTb + nX;
  short* ypart = PTTb + nPT;                         // 2 halves

  prep<<<NTX + NPT + NCV, 256, 0, stream>>>(x, R, PT, XTb, PTTb, Rb);

  stageA<<<BB * CC * 2, 1024, 0, stream>>>(Rb, XTb, ypart);
  fusedB<<<BB * OCC * 2 * 4, 512, 0, stream>>>(ypart, P, PTTb, out);
}

// Round 12
// 207.144 us; speedup vs baseline: 1.1039x; 1.0346x over previous
//
#include <hip/hip_runtime.h>
#include <stdint.h>
#include <stddef.h>

// Problem constants
#define BB 8
#define CC 16
#define DD 192
#define OCC 4
#define OHH 50
#define OWW 200

#define LDP 200   // padded LDS row stride in bf16 elements (192 + 8)
#define CH  24    // 8-element chunks per 192 row

typedef __attribute__((ext_vector_type(8))) short s8v;   // 8 bf16 = 16B (MFMA A/B frag)
typedef __attribute__((ext_vector_type(4))) short s4v;   // 4 bf16 = 8B
typedef __attribute__((ext_vector_type(4))) float f4v;   // 4 fp32
typedef __attribute__((ext_vector_type(4))) float f32x4; // MFMA C/D frag

__device__ __forceinline__ short rne_bf16(float f) {
  uint32_t u = __float_as_uint(f);
  u += 0x7fffu + ((u >> 16) & 1u);
  return (short)(u >> 16);
}
__device__ __forceinline__ float bf2f(short s) {
  return __uint_as_float(((uint32_t)(uint16_t)s) << 16);
}

// ---------------- fused prep kernel ----------------
// z-segmented grid: [0, NTX)      transpose_x   (x fp32 -> XTb bf16 transposed)
//                   [NTX, +NPT)   transpose_pt  (PT fp32 -> PTTb bf16 transposed)
//                   [.., +NCV)    cvt R fp32 -> bf16  (separate from stageA: R9
//                   proved in-stageA cvt costs +22us on the serialized path)
// Transposes tiled 64x32 so BOTH phases issue 128B transactions
// (read: 32 lanes x 4B fp32; write: 64 lanes x 2B bf16). Old 32x32 wrote 64B.
#define NTX (BB * CC * 18)    // 2304 blocks: 3(p) x 6(q) 64x32-tiles per outer
#define NPT (OCC * CC * 21)   // 1344 blocks: 3(q) x 7(n) 64x32-tiles per outer
#define NCV 9216              // (16*16*192*192/4)/256

__global__ __launch_bounds__(256) void prep(const float* __restrict__ x,
                                            const float* __restrict__ R,
                                            const float* __restrict__ PT,
                                            short* __restrict__ XTb,
                                            short* __restrict__ PTTb,
                                            short* __restrict__ Rb) {
  __shared__ float tile[64][33];   // 8.4 KB; stride 33 == 1 mod 32 -> 2-way free
  const int z = blockIdx.x;
  const int tid = threadIdx.x;
  if (z < NTX) {
    int outer = z / 18, rem = z % 18;
    int p0 = (rem / 6) * 64, q0 = (rem % 6) * 32;
    const float* src = x + (size_t)outer * DD * DD;
    {
      int col = tid & 31, r0 = tid >> 5;            // 64 rows x 32 cols in
      #pragma unroll
      for (int k = 0; k < 8; ++k) {
        int r = r0 + k * 8;
        tile[r][col] = src[(size_t)(p0 + r) * DD + q0 + col];
      }
    }
    __syncthreads();
    short* dst = XTb + (size_t)outer * DD * DD;
    {
      int qq = tid & 63, n0r = tid >> 6;            // 32 rows x 64 cols out
      #pragma unroll
      for (int k = 0; k < 8; ++k) {
        int nn = n0r + k * 4;
        dst[(size_t)(q0 + nn) * DD + p0 + qq] = rne_bf16(tile[qq][nn]);
      }
    }
  } else if (z < NTX + NPT) {
    int z2 = z - NTX;
    int outer = z2 / 21, rem = z2 % 21;
    int q0 = (rem / 7) * 64, n0 = (rem % 7) * 32;
    const float* src = PT + (size_t)outer * DD * OWW;
    {
      int col = tid & 31, r0 = tid >> 5;            // 64 q-rows x 32 n-cols in
      #pragma unroll
      for (int k = 0; k < 8; ++k) {
        int r = r0 + k * 8;
        tile[r][col] = (n0 + col < OWW) ? src[(size_t)(q0 + r) * OWW + n0 + col] : 0.f;
      }
    }
    __syncthreads();
    short* dst = PTTb + (size_t)outer * OWW * DD;
    {
      int qq = tid & 63, n0r = tid >> 6;            // 32 n-rows x 64 q-cols out
      #pragma unroll
      for (int k = 0; k < 8; ++k) {
        int nn = n0r + k * 4;
        if (n0 + nn < OWW)
          dst[(size_t)(n0 + nn) * DD + q0 + qq] = rne_bf16(tile[qq][nn]);
      }
    }
  } else {
    int idx = (z - NTX - NPT) * 256 + tid;   // exact: NCV*256 == nR/4
    f4v v = *(const f4v*)(R + (size_t)idx * 4);
    s4v o;
    #pragma unroll
    for (int r = 0; r < 4; ++r) o[r] = rne_bf16(v[r]);
    *(s4v*)(Rb + (size_t)idx * 4) = o;
  }
}

// ---------------- stage A ----------------
// EXACT R5/R10 kernel (proven 74.4-75.2 us): 1024 threads = 16 waves, 4x4 wave
// grid, 3x3 16-tiles per wave, cached vector-load staging, LDP=200 padding,
// XCD-chunked blockIdx swizzle. Ledger of slower variants -- do NOT reintroduce:
// direct-global A-frags (+70us), register prefetch (spill, x2), global_load_lds
// (+50us, no cache dedup), in-kernel fp32-R cvt (+22us), rf-cache (R9 bundle).
// 773 TF ~= 86% of the 2-barrier-structure ceiling.
__global__ __launch_bounds__(1024) void stageA(const short* __restrict__ Rb,
                                               const short* __restrict__ XTb,
                                               short* __restrict__ ypart) {
  __shared__ __align__(16) short ldsR[DD * LDP];
  __shared__ __align__(16) short lds2[DD * LDP];
  const int tid = threadIdx.x;
  const int bx0 = blockIdx.x;
  const int bx = (bx0 & 7) * 32 + (bx0 >> 3);   // XCD-chunked swizzle (256 = 8*32, bijective)
  const int b = bx >> 5, i = (bx >> 1) & 15, jg = bx & 1;
  const int lane15 = tid & 15, quad = (tid & 63) >> 4;
  const int wid = tid >> 6;   // 0..15
  const int wm = wid & 3;     // 4 groups x 3 tiles (B-operand dim)
  const int wq = wid >> 2;    // 4 groups x 3 tiles (A-operand dim)

  f32x4 acc_y[3][3];
  #pragma unroll
  for (int a = 0; a < 3; ++a)
    #pragma unroll
    for (int c = 0; c < 3; ++c) acc_y[a][c] = (f32x4){0.f, 0.f, 0.f, 0.f};

  for (int jj = 0; jj < 8; ++jj) {
    const int j = jg * 8 + jj;
    const short* srcR = Rb + (size_t)(i * CC + j) * (DD * DD);
    const short* srcX = XTb + (size_t)(b * CC + j) * (DD * DD);
    __syncthreads();  // previous iter done reading ldsR/lds2
    for (int c = tid; c < DD * CH; c += 1024) {
      int row = c / CH, col = c % CH;
      *(s8v*)(&ldsR[row * LDP + col * 8]) = *(const s8v*)(srcR + (size_t)c * 8);
      *(s8v*)(&lds2[row * LDP + col * 8]) = *(const s8v*)(srcX + (size_t)c * 8);
    }
    __syncthreads();

    // mm1: T^T  (A = XT rows -> wq covers 3 q-tiles; B = R rows -> wm covers 3 m-tiles)
    f32x4 acc_t[3][3];
    #pragma unroll
    for (int a = 0; a < 3; ++a)
      #pragma unroll
      for (int c = 0; c < 3; ++c) acc_t[a][c] = (f32x4){0.f, 0.f, 0.f, 0.f};

    #pragma unroll
    for (int kc = 0; kc < 6; ++kc) {
      s8v af[3], bf[3];
      #pragma unroll
      for (int a = 0; a < 3; ++a)
        af[a] = *(const s8v*)(&lds2[((wq * 3 + a) * 16 + lane15) * LDP + kc * 32 + quad * 8]);
      #pragma unroll
      for (int c = 0; c < 3; ++c)
        bf[c] = *(const s8v*)(&ldsR[((wm * 3 + c) * 16 + lane15) * LDP + kc * 32 + quad * 8]);
      #pragma unroll
      for (int a = 0; a < 3; ++a)
        #pragma unroll
        for (int c = 0; c < 3; ++c)
          acc_t[a][c] = __builtin_amdgcn_mfma_f32_16x16x32_bf16(af[a], bf[c], acc_t[a][c], 0, 0, 0);
    }
    __syncthreads();   // X fully consumed

    // pack T[m][q] (bf16) into lds2
    #pragma unroll
    for (int a = 0; a < 3; ++a) {
      #pragma unroll
      for (int c = 0; c < 3; ++c) {
        s4v pk;
        #pragma unroll
        for (int r = 0; r < 4; ++r) pk[r] = rne_bf16(acc_t[a][c][r]);
        int m = (wm * 3 + c) * 16 + lane15;
        int q0 = (wq * 3 + a) * 16 + quad * 4;
        *(s4v*)(&lds2[m * LDP + q0]) = pk;
      }
    }
    __syncthreads();

    // mm2: y[m][n] += T rows x R rows  (A = T -> wq covers 3 m-tiles; B = R -> wm covers 3 n-tiles)
    #pragma unroll
    for (int kc = 0; kc < 6; ++kc) {
      s8v af[3], bf[3];
      #pragma unroll
      for (int a = 0; a < 3; ++a)
        af[a] = *(const s8v*)(&lds2[((wq * 3 + a) * 16 + lane15) * LDP + kc * 32 + quad * 8]);
      #pragma unroll
      for (int c = 0; c < 3; ++c)
        bf[c] = *(const s8v*)(&ldsR[((wm * 3 + c) * 16 + lane15) * LDP + kc * 32 + quad * 8]);
      #pragma unroll
      for (int a = 0; a < 3; ++a)
        #pragma unroll
        for (int c = 0; c < 3; ++c)
          acc_y[a][c] = __builtin_amdgcn_mfma_f32_16x16x32_bf16(af[a], bf[c], acc_y[a][c], 0, 0, 0);
    }
  }

  // pack y^T [n][m] into lds2, then coalesced store
  __syncthreads();
  #pragma unroll
  for (int a = 0; a < 3; ++a) {
    #pragma unroll
    for (int c = 0; c < 3; ++c) {
      s4v pk;
      #pragma unroll
      for (int r = 0; r < 4; ++r) pk[r] = rne_bf16(acc_y[a][c][r]);
      int n = (wm * 3 + c) * 16 + lane15;       // B-row = n (col of y)
      int m0 = (wq * 3 + a) * 16 + quad * 4;    // A-row = m, 4 consecutive
      *(s4v*)(&lds2[n * LDP + m0]) = pk;
    }
  }
  __syncthreads();
  {
    short* dst = ypart + (size_t)(jg * (BB * CC) + b * CC + i) * (DD * DD);
    for (int c = tid; c < DD * CH; c += 1024) {
      int row = c / CH, col = c % CH;
      *(s8v*)(dst + (size_t)c * 8) = *(const s8v*)(&lds2[row * LDP + col * 8]);
    }
  }
}

// ---------------- fused stage B ----------------
// out[b,oc] = sum_j P[oc,j] @ y[b,j] @ PT[oc,j]
// y = ypart0 + ypart1 summed during staging; P staged from fp32 (cvt fused).
// Final store: atomicAdd into out (harness memsets out to 0 before launch);
// each out element receives exactly 4 adds (one per jg partial).
#define PROWS 64
#define PTROWS 128
__global__ __launch_bounds__(512, 2) void fusedB(const short* __restrict__ ypart,
                                                 const float* __restrict__ Pf,
                                                 const short* __restrict__ PTTb,
                                                 float* __restrict__ out) {
  __shared__ __align__(16) short ldsYT[DD * LDP];     // 76.8 KB; rows 0..63 reused for U
  __shared__ __align__(16) short ldsP[PROWS * LDP];   // 25.6 KB
  __shared__ __align__(16) short ldsPT[PTROWS * LDP]; // 51.2 KB
  const int tid = threadIdx.x;
  const int bx0 = blockIdx.x;
  const int bx = (bx0 & 7) * 32 + (bx0 >> 3);   // XCD-chunked swizzle
  const int jg = bx & 3, nh = (bx >> 2) & 1, oc = (bx >> 3) & 3, b = bx >> 5;
  const int lane15 = tid & 15, quad = (tid & 63) >> 4;
  const int wid = tid >> 6;
  // mm_b1 wave grid: 4 (q) x 2 (m)
  const int wq1 = wid >> 1, wm1 = wid & 1;
  // mm_b2 wave grid: 2 (m) x 4 (n)
  const int wm2 = wid & 1, wn2 = wid >> 1;

  f32x4 acc_o[2][2];
  #pragma unroll
  for (int a = 0; a < 2; ++a)
    #pragma unroll
    for (int e = 0; e < 2; ++e) acc_o[a][e] = (f32x4){0.f, 0.f, 0.f, 0.f};

  const s8v z = {0, 0, 0, 0, 0, 0, 0, 0};
  for (int jj = 0; jj < 4; ++jj) {
    const int j = jg * 4 + jj;
    __syncthreads();  // prev iter done reading U/ldsP/ldsPT
    {
      const short* sy0 = ypart + (size_t)(b * CC + j) * (DD * DD);
      const short* sy1 = sy0 + (size_t)(BB * CC) * (DD * DD);
      for (int c = tid; c < DD * CH; c += 512) {
        int row = c / CH, col = c % CH;
        s8v v0 = *(const s8v*)(sy0 + (size_t)c * 8);
        s8v v1 = *(const s8v*)(sy1 + (size_t)c * 8);
        s8v o;
        #pragma unroll
        for (int r = 0; r < 8; ++r) o[r] = rne_bf16(bf2f(v0[r]) + bf2f(v1[r]));
        *(s8v*)(&ldsYT[row * LDP + col * 8]) = o;
      }
      const float* sp = Pf + (size_t)(oc * CC + j) * (OHH * DD);
      for (int c = tid; c < PROWS * CH; c += 512) {
        int row = c / CH, col = c % CH;
        s8v w = z;
        if (c < OHH * CH) {
          f4v v0 = *(const f4v*)(sp + (size_t)c * 8);
          f4v v1 = *(const f4v*)(sp + (size_t)c * 8 + 4);
          #pragma unroll
          for (int r = 0; r < 4; ++r) w[r] = rne_bf16(v0[r]);
          #pragma unroll
          for (int r = 0; r < 4; ++r) w[r + 4] = rne_bf16(v1[r]);
        }
        *(s8v*)(&ldsP[row * LDP + col * 8]) = w;
      }
      const short* st = PTTb + (size_t)(oc * CC + j) * (OWW * DD) + (size_t)nh * 100 * DD;
      for (int c = tid; c < PTROWS * CH; c += 512) {
        int row = c / CH, col = c % CH;
        *(s8v*)(&ldsPT[row * LDP + col * 8]) =
            (c < 100 * CH) ? *(const s8v*)(st + (size_t)c * 8) : z;
      }
    }
    __syncthreads();

    // mm_b1: U^T[q][m]; wq1 -> 3 q-tiles, wm1 -> 2 m-tiles
    f32x4 acc_t[3][2];
    #pragma unroll
    for (int a = 0; a < 3; ++a)
      #pragma unroll
      for (int c = 0; c < 2; ++c) acc_t[a][c] = (f32x4){0.f, 0.f, 0.f, 0.f};
    #pragma unroll
    for (int kc = 0; kc < 6; ++kc) {
      s8v af[3], bf[2];
      #pragma unroll
      for (int a = 0; a < 3; ++a)
        af[a] = *(const s8v*)(&ldsYT[((wq1 * 3 + a) * 16 + lane15) * LDP + kc * 32 + quad * 8]);
      #pragma unroll
      for (int c = 0; c < 2; ++c)
        bf[c] = *(const s8v*)(&ldsP[((wm1 * 2 + c) * 16 + lane15) * LDP + kc * 32 + quad * 8]);
      #pragma unroll
      for (int a = 0; a < 3; ++a)
        #pragma unroll
        for (int c = 0; c < 2; ++c)
          acc_t[a][c] = __builtin_amdgcn_mfma_f32_16x16x32_bf16(af[a], bf[c], acc_t[a][c], 0, 0, 0);
    }
    __syncthreads();  // yT fully consumed

    // pack U[m][q] into ldsYT rows 0..63
    #pragma unroll
    for (int a = 0; a < 3; ++a) {
      #pragma unroll
      for (int c = 0; c < 2; ++c) {
        s4v pk;
        #pragma unroll
        for (int r = 0; r < 4; ++r) pk[r] = rne_bf16(acc_t[a][c][r]);
        int m = (wm1 * 2 + c) * 16 + lane15;
        int q0 = (wq1 * 3 + a) * 16 + quad * 4;
        *(s4v*)(&ldsYT[m * LDP + q0]) = pk;
      }
    }
    __syncthreads();

    // mm_b2: out[m][n] += U rows x PT^T rows; wm2 -> 2 m-tiles, wn2 -> 2 n-tiles
    #pragma unroll
    for (int kc = 0; kc < 6; ++kc) {
      s8v af[2], bf[2];
      #pragma unroll
      for (int a = 0; a < 2; ++a)
        af[a] = *(const s8v*)(&ldsYT[((wm2 * 2 + a) * 16 + lane15) * LDP + kc * 32 + quad * 8]);
      #pragma unroll
      for (int e = 0; e < 2; ++e)
        bf[e] = *(const s8v*)(&ldsPT[((wn2 * 2 + e) * 16 + lane15) * LDP + kc * 32 + quad * 8]);
      #pragma unroll
      for (int a = 0; a < 2; ++a)
        #pragma unroll
        for (int e = 0; e < 2; ++e)
          acc_o[a][e] = __builtin_amdgcn_mfma_f32_16x16x32_bf16(af[a], bf[e], acc_o[a][e], 0, 0, 0);
    }
  }

  // atomic accumulate partial into out[b*OCC+oc][m][nh*100 + n]
  float* dst = out + (size_t)(b * OCC + oc) * (OHH * OWW);
  #pragma unroll
  for (int a = 0; a < 2; ++a) {
    #pragma unroll
    for (int e = 0; e < 2; ++e) {
      int n = (wn2 * 2 + e) * 16 + lane15;
      if (n < 100) {
        #pragma unroll
        for (int r = 0; r < 4; ++r) {
          int m = (wm2 * 2 + a) * 16 + quad * 4 + r;
          if (m < OHH)
            atomicAdd(&dst[(size_t)m * OWW + nh * 100 + n], acc_o[a][e][r]);
        }
      }
    }
  }
}

// ---------------- launcher ----------------

extern "C" void kernel_launch(void* const* d_in, const int* in_sizes, int n_in,
                              void* d_out, int out_size, void* d_ws, size_t ws_size,
                              hipStream_t stream) {
  const float* x  = (const float*)d_in[0];
  const float* R  = (const float*)d_in[1];
  const float* P  = (const float*)d_in[2];
  const float* PT = (const float*)d_in[3];
  float* out = (float*)d_out;

  short* W = (short*)d_ws;
  const size_t nR   = (size_t)CC * CC * DD * DD;     // 9,437,184
  const size_t nX   = (size_t)BB * CC * DD * DD;     // 4,718,592
  const size_t nPT  = (size_t)OCC * CC * OWW * DD;   // 2,457,600
  short* Rb    = W;
  short* XTb   = Rb + nR;
  short* PTTb  = XTb + nX;
  short* ypart = PTTb + nPT;                         // 2 halves

  prep<<<NTX + NPT + NCV, 256, 0, stream>>>(x, R, PT, XTb, PTTb, Rb);

  stageA<<<BB * CC * 2, 1024, 0, stream>>>(Rb, XTb, ypart);
  fusedB<<<BB * OCC * 2 * 4, 512, 0, stream>>>(ypart, P, PTTb, out);
}